// Round 1
// baseline (162.536 us; speedup 1.0000x reference)
//
#include <hip/hip_runtime.h>
#include <math.h>

#define NPTS 200
#define NCH  13
#define BLK  256
#define FPB  (NPTS * NCH)          // 2600 floats per batch
#define STG  2560                  // floats staged in LDS: covers points 0..191 fully

// 4-byte-aligned float4 for dword-aligned (not 16B-aligned) vector loads
typedef float f4u __attribute__((ext_vector_type(4), aligned(4)));

// 12-byte packed store (align 4) for coalesced per-point output
typedef struct { float x, y, z; } f3s;

#define ACCUMULATE(Q0,Q1,Q2,Q3,Q4,Q5,Q6,Q7,Q8,Q9,Q10,Q11,Q12)               \
    {                                                                        \
        float wt = aa * (Q0) + bb;                                           \
        wt = fmaxf(wt, 0.f) + 1e-8f;                                         \
        const float v1x = fmaf(shift, (Q7),  (Q1));                          \
        const float v1y = fmaf(shift, (Q8),  (Q2));                          \
        const float v1z = fmaf(shift, (Q9),  (Q3));                          \
        const float v2x = fmaf(shift, (Q10), (Q4));                          \
        const float v2y = fmaf(shift, (Q11), (Q5));                          \
        const float v2z = fmaf(shift, (Q12), (Q6));                          \
        const float wv2x = wt * v2x, wv2y = wt * v2y, wv2z = wt * v2z;       \
        acc[0] += wt;                                                        \
        acc[1] += wt * v1x; acc[2] += wt * v1y; acc[3] += wt * v1z;          \
        acc[4] += wv2x;     acc[5] += wv2y;     acc[6] += wv2z;              \
        acc[7]  += wv2x * v1x; acc[8]  += wv2x * v1y; acc[9]  += wv2x * v1z; \
        acc[10] += wv2y * v1x; acc[11] += wv2y * v1y; acc[12] += wv2y * v1z; \
        acc[13] += wv2z * v1x; acc[14] += wv2z * v1y; acc[15] += wv2z * v1z; \
    }

// ---------------------------------------------------------------------------
// Fully fused: one wave owns one batch end-to-end.
//   stage (global_load_lds, 40.0 KB/block -> 4 blocks/CU)
//   -> weighted sums (per-lane, 3 pts from LDS + tail pt from regs)
//   -> 6-level shfl_xor butterfly: ALL lanes hold all 16 sums (no LDS transpose)
//   -> 5-sweep 4x4 Jacobi, redundant on all 64 lanes (VALU overlaps other
//      waves' HBM staging; no broadcast needed)
//   -> apply R,t to xyz2 SAVED IN REGISTERS during the reduce pass
//      (zero re-read of net_in), coalesced 12B/lane stores.
// Zero __syncthreads, zero workspace, one dispatch.
// ---------------------------------------------------------------------------
__global__ __launch_bounds__(BLK, 4) void fused_kernel(
    const float* __restrict__ net_in,   // (B, 200, 13)
    const float* __restrict__ shift_p,
    const float* __restrict__ a_p,
    const float* __restrict__ b_p,
    float* __restrict__ out)            // (B, 200, 3)
{
    __shared__ float s_in[4 * STG];     // 40,960 B exactly -> 4 blocks/CU

    const int tid = threadIdx.x;
    const int w   = tid >> 6;             // wave id = local batch
    const int l   = tid & 63;
    const int b   = blockIdx.x * 4 + w;   // global batch

    const float shift = shift_p[0];
    const float aa    = a_p[0];
    const float bb    = b_p[0];

    const float* src = net_in + (size_t)b * FPB;
    float*       dst = s_in + w * STG;    // wave-private LDS region

    // ---- async stage: 640 float4 -> LDS (points 0..191 fully covered) ----
    #pragma unroll
    for (int j = 0; j < 10; ++j) {
        __builtin_amdgcn_global_load_lds(
            (const __attribute__((address_space(1))) void*)(src + j * 256 + l * 4),
            (__attribute__((address_space(3))) void*)(dst + j * 256),
            16, 0, 0);
    }

    // ---- tail points 192..199 direct to registers (same vmcnt drain) ----
    f4u t0v = {0.f, 0.f, 0.f, 0.f};
    f4u t1v = {0.f, 0.f, 0.f, 0.f};
    f4u t2v = {0.f, 0.f, 0.f, 0.f};
    float t12 = 0.f;
    if (l < 8) {
        const float* tp = src + (192 + l) * NCH;
        t0v = *(const f4u*)(tp);        // q0..q3
        t1v = *(const f4u*)(tp + 4);    // q4..q7
        t2v = *(const f4u*)(tp + 8);    // q8..q11
        t12 = tp[12];                   // q12
    }

    __builtin_amdgcn_s_waitcnt(0);          // drain this wave's staging + tail
    __asm__ __volatile__("" ::: "memory");  // keep LDS reads below the wait

    // ---- per-lane accumulation; save xyz2 in registers for the apply step ----
    float acc[16];
    #pragma unroll
    for (int k = 0; k < 16; ++k) acc[k] = 0.f;

    float sx2[4], sy2[4], sz2[4];

    #pragma unroll
    for (int j = 0; j < 3; ++j) {
        const int p = l + 64 * j;           // stride-52B: 2-way LDS alias = free
        const float* q = dst + p * NCH;
        const float q0 = q[0],  q1 = q[1],  q2  = q[2],  q3  = q[3];
        const float q4 = q[4],  q5 = q[5],  q6  = q[6],  q7  = q[7];
        const float q8 = q[8],  q9 = q[9],  q10 = q[10], q11 = q[11], q12 = q[12];
        ACCUMULATE(q0, q1, q2, q3, q4, q5, q6, q7, q8, q9, q10, q11, q12)
        sx2[j] = q4; sy2[j] = q5; sz2[j] = q6;
    }
    sx2[3] = t1v.x; sy2[3] = t1v.y; sz2[3] = t1v.z;   // zero-init for l>=8
    if (l < 8) {
        ACCUMULATE(t0v.x, t0v.y, t0v.z, t0v.w,
                   t1v.x, t1v.y, t1v.z, t1v.w,
                   t2v.x, t2v.y, t2v.z, t2v.w, t12)
    }

    // ---- full 64-lane xor-butterfly: every lane ends with all 16 totals ----
    #pragma unroll
    for (int k = 0; k < 16; ++k) {
        acc[k] += __shfl_xor(acc[k], 32, 64);
        acc[k] += __shfl_xor(acc[k], 16, 64);
        acc[k] += __shfl_xor(acc[k],  8, 64);
        acc[k] += __shfl_xor(acc[k],  4, 64);
        acc[k] += __shfl_xor(acc[k],  2, 64);
        acc[k] += __shfl_xor(acc[k],  1, 64);
    }

    // ---- Horn quaternion / 4x4 Jacobi, redundant on all lanes (uniform) ----
    const float W = acc[0];
    const float invW = 1.0f / W;
    const float v1cx = acc[1] * invW, v1cy = acc[2] * invW, v1cz = acc[3] * invW;
    const float v2cx = acc[4] * invW, v2cy = acc[5] * invW, v2cz = acc[6] * invW;

    const float Sxx = acc[7]  - W * v2cx * v1cx;
    const float Sxy = acc[8]  - W * v2cx * v1cy;
    const float Sxz = acc[9]  - W * v2cx * v1cz;
    const float Syx = acc[10] - W * v2cy * v1cx;
    const float Syy = acc[11] - W * v2cy * v1cy;
    const float Syz = acc[12] - W * v2cy * v1cz;
    const float Szx = acc[13] - W * v2cz * v1cx;
    const float Szy = acc[14] - W * v2cz * v1cy;
    const float Szz = acc[15] - W * v2cz * v1cz;

    float Am[4][4];
    Am[0][0] = Sxx + Syy + Szz;
    Am[0][1] = Syz - Szy;  Am[0][2] = Szx - Sxz;  Am[0][3] = Sxy - Syx;
    Am[1][1] = Sxx - Syy - Szz;
    Am[1][2] = Sxy + Syx;  Am[1][3] = Szx + Sxz;
    Am[2][2] = -Sxx + Syy - Szz;
    Am[2][3] = Syz + Szy;
    Am[3][3] = -Sxx - Syy + Szz;
    Am[1][0] = Am[0][1]; Am[2][0] = Am[0][2]; Am[3][0] = Am[0][3];
    Am[2][1] = Am[1][2]; Am[3][1] = Am[1][3]; Am[3][2] = Am[2][3];

    float Vm[4][4] = {{1,0,0,0},{0,1,0,0},{0,0,1,0},{0,0,0,1}};

    const int prs[6][2] = {{0,1},{0,2},{0,3},{1,2},{1,3},{2,3}};
    for (int sweep = 0; sweep < 5; ++sweep) {
        #pragma unroll
        for (int r = 0; r < 6; ++r) {
            const int p = prs[r][0], q = prs[r][1];
            float apq = Am[p][q];
            if (apq != 0.0f) {                       // uniform: lanes identical
                float tau = (Am[q][q] - Am[p][p]) / (2.0f * apq);
                float t = copysignf(1.0f, tau) /
                          (fabsf(tau) + sqrtf(1.0f + tau * tau));
                float c = rsqrtf(1.0f + t * t);
                float s = t * c;
                #pragma unroll
                for (int k = 0; k < 4; ++k) {
                    float a1 = Am[p][k], a2 = Am[q][k];
                    Am[p][k] = c * a1 - s * a2;
                    Am[q][k] = s * a1 + c * a2;
                }
                #pragma unroll
                for (int k = 0; k < 4; ++k) {
                    float a1 = Am[k][p], a2 = Am[k][q];
                    Am[k][p] = c * a1 - s * a2;
                    Am[k][q] = s * a1 + c * a2;
                }
                #pragma unroll
                for (int k = 0; k < 4; ++k) {
                    float a1 = Vm[k][p], a2 = Vm[k][q];
                    Vm[k][p] = c * a1 - s * a2;
                    Vm[k][q] = s * a1 + c * a2;
                }
            }
        }
    }

    // ---- best eigenvector: constant-indexed compare chain (no scratch) ----
    float bd = Am[0][0];
    float q0 = Vm[0][0], qx = Vm[1][0], qy = Vm[2][0], qz = Vm[3][0];
    if (Am[1][1] > bd) { bd = Am[1][1]; q0 = Vm[0][1]; qx = Vm[1][1]; qy = Vm[2][1]; qz = Vm[3][1]; }
    if (Am[2][2] > bd) { bd = Am[2][2]; q0 = Vm[0][2]; qx = Vm[1][2]; qy = Vm[2][2]; qz = Vm[3][2]; }
    if (Am[3][3] > bd) { bd = Am[3][3]; q0 = Vm[0][3]; qx = Vm[1][3]; qy = Vm[2][3]; qz = Vm[3][3]; }

    const float R00 = q0*q0 + qx*qx - qy*qy - qz*qz;
    const float R01 = 2.0f * (qx*qy - q0*qz);
    const float R02 = 2.0f * (qx*qz + q0*qy);
    const float R10 = 2.0f * (qx*qy + q0*qz);
    const float R11 = q0*q0 - qx*qx + qy*qy - qz*qz;
    const float R12 = 2.0f * (qy*qz - q0*qx);
    const float R20 = 2.0f * (qx*qz - q0*qy);
    const float R21 = 2.0f * (qy*qz + q0*qx);
    const float R22 = q0*q0 - qx*qx - qy*qy + qz*qz;

    const float tx = v1cx - (R00 * v2cx + R01 * v2cy + R02 * v2cz);
    const float ty = v1cy - (R10 * v2cx + R11 * v2cy + R12 * v2cz);
    const float tz = v1cz - (R20 * v2cx + R21 * v2cy + R22 * v2cz);

    // ---- apply from registers; 12B/lane contiguous stores (768B/instr) ----
    float* ob = out + (size_t)b * (NPTS * 3);
    #pragma unroll
    for (int j = 0; j < 4; ++j) {
        if (j < 3 || l < 8) {
            const int p = l + 64 * j;
            const float X = sx2[j], Y = sy2[j], Z = sz2[j];
            f3s o3;
            o3.x = R00 * X + R01 * Y + R02 * Z + tx;
            o3.y = R10 * X + R11 * Y + R12 * Z + ty;
            o3.z = R20 * X + R21 * Y + R22 * Z + tz;
            *(f3s*)(ob + p * 3) = o3;
        }
    }
}

extern "C" void kernel_launch(void* const* d_in, const int* in_sizes, int n_in,
                              void* d_out, int out_size, void* d_ws, size_t ws_size,
                              hipStream_t stream) {
    const float* net_in  = (const float*)d_in[0];
    const float* shift_p = (const float*)d_in[1];
    const float* a_p     = (const float*)d_in[2];
    const float* b_p     = (const float*)d_in[3];
    float* out = (float*)d_out;

    const int B = in_sizes[0] / FPB;             // 8192
    (void)d_ws; (void)ws_size; (void)n_in; (void)out_size;

    fused_kernel<<<B / 4, BLK, 0, stream>>>(net_in, shift_p, a_p, b_p, out);
}

// Round 2
// 144.387 us; speedup vs baseline: 1.1257x; 1.1257x over previous
//
#include <hip/hip_runtime.h>
#include <math.h>

#define NPTS 200
#define NCH  13
#define BLK  256
#define FPB  (NPTS * NCH)          // 2600 floats per batch

// 4-byte-aligned float4 for dword-aligned (not 16B-aligned) vector loads
typedef float f4u __attribute__((ext_vector_type(4), aligned(4)));

// 12-byte packed store (align 4) for coalesced per-point output
typedef struct { float x, y, z; } f3s;

#define ACCUMULATE(Q0,Q1,Q2,Q3,Q4,Q5,Q6,Q7,Q8,Q9,Q10,Q11,Q12)               \
    {                                                                        \
        float wt = aa * (Q0) + bb;                                           \
        wt = fmaxf(wt, 0.f) + 1e-8f;                                         \
        const float v1x = fmaf(shift, (Q7),  (Q1));                          \
        const float v1y = fmaf(shift, (Q8),  (Q2));                          \
        const float v1z = fmaf(shift, (Q9),  (Q3));                          \
        const float v2x = fmaf(shift, (Q10), (Q4));                          \
        const float v2y = fmaf(shift, (Q11), (Q5));                          \
        const float v2z = fmaf(shift, (Q12), (Q6));                          \
        const float wv2x = wt * v2x, wv2y = wt * v2y, wv2z = wt * v2z;       \
        acc[0] += wt;                                                        \
        acc[1] += wt * v1x; acc[2] += wt * v1y; acc[3] += wt * v1z;          \
        acc[4] += wv2x;     acc[5] += wv2y;     acc[6] += wv2z;              \
        acc[7]  += wv2x * v1x; acc[8]  += wv2x * v1y; acc[9]  += wv2x * v1z; \
        acc[10] += wv2y * v1x; acc[11] += wv2y * v1y; acc[12] += wv2y * v1z; \
        acc[13] += wv2z * v1x; acc[14] += wv2z * v1y; acc[15] += wv2z * v1z; \
    }

// ---------------------------------------------------------------------------
// Fused v2: one wave per batch for the memory phases, but the 4x4 Jacobi
// runs SIMT (one THREAD per batch, threads 0-3 of the block) — 64x less
// instruction issue than the per-wave-scalar solve of v1 (which was ~35us
// of pure VALU issue: IEEE div/sqrt sequences x 30 rotations x 8192 waves).
//
//   - direct f4u loads (no LDS staging: data has zero reuse; frees 40KB LDS
//     and the full-drain waitcnt stall; xyz2 kept in registers for apply)
//   - 2-level shfl + 16x16 LDS transpose -> 16 totals per batch in LDS
//   - threads 0-3: Jacobi with HW v_rcp/v_sqrt/v_rsq approximations
//     (+ final quaternion renorm for orthogonality), R|t -> LDS
//   - broadcast R,t; apply from registers; coalesced 12B/lane stores
// Two __syncthreads, ~5.6KB LDS, one dispatch.
// ---------------------------------------------------------------------------
__global__ __launch_bounds__(BLK, 4) void fused_kernel(
    const float* __restrict__ net_in,   // (B, 200, 13)
    const float* __restrict__ shift_p,
    const float* __restrict__ a_p,
    const float* __restrict__ b_p,
    float* __restrict__ out)            // (B, 200, 3)
{
    __shared__ float s_part[4][16][20];   // per-wave 16x16 transpose (+pad)
    __shared__ float s_sums[4][16];       // 16 totals per batch
    __shared__ float s_Rt[4][12];         // R (9) + t (3) per batch

    const int tid = threadIdx.x;
    const int w   = tid >> 6;             // wave id = local batch
    const int l   = tid & 63;
    const int b   = blockIdx.x * 4 + w;   // global batch

    const float shift = shift_p[0];
    const float aa    = a_p[0];
    const float bb    = b_p[0];

    const float* src = net_in + (size_t)b * FPB;

    // ---- per-lane accumulation straight from global (52B/lane, coalesced;
    //      compiler software-pipelines the 16 loads) ----
    float acc[16];
    #pragma unroll
    for (int k = 0; k < 16; ++k) acc[k] = 0.f;

    float sx2[4], sy2[4], sz2[4];

    #pragma unroll
    for (int j = 0; j < 4; ++j) {
        if (j < 3 || l < 8) {             // j<3 always valid; j==3 only l<8
            const float* q = src + (l + 64 * j) * NCH;
            const f4u v0 = *(const f4u*)(q);      // w, x1,y1,z1
            const f4u v1 = *(const f4u*)(q + 4);  // x2,y2,z2, n1x
            const f4u v2 = *(const f4u*)(q + 8);  // n1y,n1z, n2x,n2y
            const float q12 = q[12];              // n2z
            ACCUMULATE(v0.x, v0.y, v0.z, v0.w,
                       v1.x, v1.y, v1.z, v1.w,
                       v2.x, v2.y, v2.z, v2.w, q12)
            sx2[j] = v1.x; sy2[j] = v1.y; sz2[j] = v1.z;
        } else {
            sx2[j] = 0.f; sy2[j] = 0.f; sz2[j] = 0.f;
        }
    }

    // ---- 64 -> 16 lanes, then 16x16 transpose; totals -> s_sums[w][*] ----
    #pragma unroll
    for (int k = 0; k < 16; ++k) {
        acc[k] += __shfl_down(acc[k], 32, 64);
        acc[k] += __shfl_down(acc[k], 16, 64);
    }
    if (l < 16) {
        float4* pp = (float4*)&s_part[w][l][0];
        pp[0] = make_float4(acc[0],  acc[1],  acc[2],  acc[3]);
        pp[1] = make_float4(acc[4],  acc[5],  acc[6],  acc[7]);
        pp[2] = make_float4(acc[8],  acc[9],  acc[10], acc[11]);
        pp[3] = make_float4(acc[12], acc[13], acc[14], acc[15]);
        float s = 0.f;
        #pragma unroll
        for (int r = 0; r < 16; ++r) s += s_part[w][r][l];
        s_sums[w][l] = s;                 // total of component l, batch w
    }
    __syncthreads();

    // ---- SIMT solve: thread t (t<4) handles batch t of this block ----
    if (tid < 4) {
        float f[16];
        #pragma unroll
        for (int k = 0; k < 16; ++k) f[k] = s_sums[tid][k];

        const float W = f[0];
        const float invW = __builtin_amdgcn_rcpf(W);
        const float v1cx = f[1] * invW, v1cy = f[2] * invW, v1cz = f[3] * invW;
        const float v2cx = f[4] * invW, v2cy = f[5] * invW, v2cz = f[6] * invW;

        const float Sxx = f[7]  - W * v2cx * v1cx;
        const float Sxy = f[8]  - W * v2cx * v1cy;
        const float Sxz = f[9]  - W * v2cx * v1cz;
        const float Syx = f[10] - W * v2cy * v1cx;
        const float Syy = f[11] - W * v2cy * v1cy;
        const float Syz = f[12] - W * v2cy * v1cz;
        const float Szx = f[13] - W * v2cz * v1cx;
        const float Szy = f[14] - W * v2cz * v1cy;
        const float Szz = f[15] - W * v2cz * v1cz;

        float Am[4][4];
        Am[0][0] = Sxx + Syy + Szz;
        Am[0][1] = Syz - Szy;  Am[0][2] = Szx - Sxz;  Am[0][3] = Sxy - Syx;
        Am[1][1] = Sxx - Syy - Szz;
        Am[1][2] = Sxy + Syx;  Am[1][3] = Szx + Sxz;
        Am[2][2] = -Sxx + Syy - Szz;
        Am[2][3] = Syz + Szy;
        Am[3][3] = -Sxx - Syy + Szz;
        Am[1][0] = Am[0][1]; Am[2][0] = Am[0][2]; Am[3][0] = Am[0][3];
        Am[2][1] = Am[1][2]; Am[3][1] = Am[1][3]; Am[3][2] = Am[2][3];

        float Vm[4][4] = {{1,0,0,0},{0,1,0,0},{0,0,1,0},{0,0,0,1}};

        const int prs[6][2] = {{0,1},{0,2},{0,3},{1,2},{1,3},{2,3}};
        for (int sweep = 0; sweep < 5; ++sweep) {
            #pragma unroll
            for (int r = 0; r < 6; ++r) {
                const int p = prs[r][0], q = prs[r][1];
                float apq = Am[p][q];
                if (apq != 0.0f) {
                    // HW approx rcp/sqrt/rsq: ~3x fewer instrs than IEEE seqs
                    float tau = (Am[q][q] - Am[p][p]) * 0.5f *
                                __builtin_amdgcn_rcpf(apq);
                    float t = copysignf(1.0f, tau) * __builtin_amdgcn_rcpf(
                                fabsf(tau) +
                                __builtin_amdgcn_sqrtf(fmaf(tau, tau, 1.0f)));
                    float c = __builtin_amdgcn_rsqf(fmaf(t, t, 1.0f));
                    float s = t * c;
                    #pragma unroll
                    for (int k = 0; k < 4; ++k) {
                        float a1 = Am[p][k], a2 = Am[q][k];
                        Am[p][k] = c * a1 - s * a2;
                        Am[q][k] = s * a1 + c * a2;
                    }
                    #pragma unroll
                    for (int k = 0; k < 4; ++k) {
                        float a1 = Am[k][p], a2 = Am[k][q];
                        Am[k][p] = c * a1 - s * a2;
                        Am[k][q] = s * a1 + c * a2;
                    }
                    #pragma unroll
                    for (int k = 0; k < 4; ++k) {
                        float a1 = Vm[k][p], a2 = Vm[k][q];
                        Vm[k][p] = c * a1 - s * a2;
                        Vm[k][q] = s * a1 + c * a2;
                    }
                }
            }
        }

        // best eigenvector: constant-indexed compare chain (no scratch)
        float bd = Am[0][0];
        float q0 = Vm[0][0], qx = Vm[1][0], qy = Vm[2][0], qz = Vm[3][0];
        if (Am[1][1] > bd) { bd = Am[1][1]; q0 = Vm[0][1]; qx = Vm[1][1]; qy = Vm[2][1]; qz = Vm[3][1]; }
        if (Am[2][2] > bd) { bd = Am[2][2]; q0 = Vm[0][2]; qx = Vm[1][2]; qy = Vm[2][2]; qz = Vm[3][2]; }
        if (Am[3][3] > bd) { bd = Am[3][3]; q0 = Vm[0][3]; qx = Vm[1][3]; qy = Vm[2][3]; qz = Vm[3][3]; }

        // renormalize (approx rotations leave ~1e-5 norm drift)
        const float qn = __builtin_amdgcn_rsqf(q0*q0 + qx*qx + qy*qy + qz*qz);
        q0 *= qn; qx *= qn; qy *= qn; qz *= qn;

        const float R00 = q0*q0 + qx*qx - qy*qy - qz*qz;
        const float R01 = 2.0f * (qx*qy - q0*qz);
        const float R02 = 2.0f * (qx*qz + q0*qy);
        const float R10 = 2.0f * (qx*qy + q0*qz);
        const float R11 = q0*q0 - qx*qx + qy*qy - qz*qz;
        const float R12 = 2.0f * (qy*qz - q0*qx);
        const float R20 = 2.0f * (qx*qz - q0*qy);
        const float R21 = 2.0f * (qy*qz + q0*qx);
        const float R22 = q0*q0 - qx*qx - qy*qy + qz*qz;

        float* o = &s_Rt[tid][0];
        o[0] = R00; o[1]  = R01; o[2]  = R02;
        o[3] = R10; o[4]  = R11; o[5]  = R12;
        o[6] = R20; o[7]  = R21; o[8]  = R22;
        o[9]  = v1cx - (R00 * v2cx + R01 * v2cy + R02 * v2cz);
        o[10] = v1cy - (R10 * v2cx + R11 * v2cy + R12 * v2cz);
        o[11] = v1cz - (R20 * v2cx + R21 * v2cy + R22 * v2cz);
    }
    __syncthreads();

    // ---- broadcast R,t (wave-uniform LDS reads) and apply from registers ----
    const float R00 = s_Rt[w][0], R01 = s_Rt[w][1],  R02 = s_Rt[w][2];
    const float R10 = s_Rt[w][3], R11 = s_Rt[w][4],  R12 = s_Rt[w][5];
    const float R20 = s_Rt[w][6], R21 = s_Rt[w][7],  R22 = s_Rt[w][8];
    const float tx  = s_Rt[w][9], ty  = s_Rt[w][10], tz  = s_Rt[w][11];

    float* ob = out + (size_t)b * (NPTS * 3);
    #pragma unroll
    for (int j = 0; j < 4; ++j) {
        if (j < 3 || l < 8) {
            const int p = l + 64 * j;
            const float X = sx2[j], Y = sy2[j], Z = sz2[j];
            f3s o3;
            o3.x = R00 * X + R01 * Y + R02 * Z + tx;
            o3.y = R10 * X + R11 * Y + R12 * Z + ty;
            o3.z = R20 * X + R21 * Y + R22 * Z + tz;
            *(f3s*)(ob + p * 3) = o3;
        }
    }
}

extern "C" void kernel_launch(void* const* d_in, const int* in_sizes, int n_in,
                              void* d_out, int out_size, void* d_ws, size_t ws_size,
                              hipStream_t stream) {
    const float* net_in  = (const float*)d_in[0];
    const float* shift_p = (const float*)d_in[1];
    const float* a_p     = (const float*)d_in[2];
    const float* b_p     = (const float*)d_in[3];
    float* out = (float*)d_out;

    const int B = in_sizes[0] / FPB;             // 8192
    (void)d_ws; (void)ws_size; (void)n_in; (void)out_size;

    fused_kernel<<<B / 4, BLK, 0, stream>>>(net_in, shift_p, a_p, b_p, out);
}